// Round 14
// baseline (80.639 us; speedup 1.0000x reference)
//
#include <hip/hip_runtime.h>
#include <stdint.h>

// Block-factorized depthwise 7x7 conv, per-(n,c,8x8-block) filters.
// feat: [N=2, C=128, H=256, W=256] f32 (NCHW)
// filters_lr: [N, C*49, 32, 32] f32 ; weight[n,hb,wb,c,t] = filt[n, c*49+t, hb, wb]
// out[n,c,h,w] = sum_t feat[n,c,h+dh-3,w+dw-3] * weight[n,h/8,w/8,c,t], t=dh*7+dw
//
// r10/r12 shuffle-halo compute, with the two remaining DRAM pathologies fixed:
//  1. COALESCED weight read: block = 8 waves = one hb-octet of one (n,c).
//     Per tap, the block needs [hb_octet x 32 wb] = 1KB CONTIGUOUS of filt ->
//     one global_load_lds width-16 (64 lanes x 16B). 49 such per block,
//     round-robined across waves. Replaces r9-r12's 128B-at-4KB-stride
//     scatter (DRAM row-buffer thrash -- the suspected 3.25 TB/s ceiling).
//  2. Nontemporal output stores (native ext_vector_type -- HIP float4 class
//     is rejected by the builtin): write stream won't evict L3-resident
//     inputs.
// Compute per wave unchanged: 14 clamped float4 row loads -> regs, bpermute
// halo (crossbar, conflict-free), wt[49] from LDS via pair-broadcast b32
// (banks 0..31, conflict-free), 1568 FMAs, 8x nt float4 stores.

#define NW 8   // waves per block

typedef const uint32_t __attribute__((address_space(1))) guint;
typedef uint32_t __attribute__((address_space(3))) luint;
typedef float __attribute__((ext_vector_type(4))) fx4;

__global__ __launch_bounds__(512, 1)
void block_fac_kernel(const float* __restrict__ feat,
                      const float* __restrict__ filt,
                      float* __restrict__ out) {
    __shared__ float s_w[49 * 8 * 32];    // [t][hb_local][wb], 50176 B

    const int bid  = blockIdx.x;          // ((n*128)+c)*4 + g
    const int g    = bid & 3;             // hb octet
    const int c    = (bid >> 2) & 127;
    const int n    = bid >> 9;
    const int wave = threadIdx.x >> 6;    // 0..7 = hb_local
    const int lane = threadIdx.x & 63;

    const int hb = g * 8 + wave;          // this wave's weight block row
    const int H0 = hb * 8;                // first output row
    const int c0 = lane << 2;             // output col base (0..252)
    const int wb = lane >> 1;             // weight block col (0..31)

    const float* fbase  = feat + (size_t)(n * 128 + c) * 65536;
    // octet base: element (t, hb=8g, wb=0) ; per tap the octet slice is 1KB contiguous
    const float* wtbase = filt + (size_t)((n * 128 + c) * 49) * 1024 + g * 256;

    // ---- coalesced weight staging: one 1KB gld_lds per tap, waves round-robin
    for (int t = wave; t < 49; t += NW) { // wave-uniform trip count per wave
        const float* gp = wtbase + (size_t)t * 1024 + (lane << 2);  // contiguous 1KB
        float* lp = s_w + t * 256;        // wave-uniform dest; HW adds lane*16B
        __builtin_amdgcn_global_load_lds((guint*)gp, (luint*)lp, 16, 0, 0);
    }

    // ---- 14 input rows: own float4, clamped address -> unconditional
    float4 row[14];
    #pragma unroll
    for (int r = 0; r < 14; ++r) {
        int gr  = H0 - 3 + r;
        int grc = gr < 0 ? 0 : (gr > 255 ? 255 : gr);
        row[r] = *(const float4*)(fbase + (size_t)grc * 256 + c0);
    }

    __syncthreads();                      // drains weight-LDS + row loads together

    // ---- weights LDS -> reg: 49 b32, banks 0..31, lane-pair broadcast
    const float* ws = s_w + wave * 32 + wb;
    float wt[49];
    #pragma unroll
    for (int t = 0; t < 49; ++t) wt[t] = ws[t * 256];

    const int addrL = ((lane - 1) & 63) << 2;   // bpermute: pull from lane-1
    const int addrR = ((lane + 1) & 63) << 2;   // pull from lane+1
    const bool l0  = (lane == 0);
    const bool l63 = (lane == 63);

    float acc[8][4] = {};

    #pragma unroll
    for (int jj = 0; jj < 14; ++jj) {     // input row H0-3+jj ; out row a uses dh=jj-a
        const int gr = H0 - 3 + jj;       // wave-uniform validity
        float4 f = row[jj];
        if (gr < 0 || gr > 255) f = make_float4(0.f, 0.f, 0.f, 0.f);

        float L1 = __int_as_float(__builtin_amdgcn_ds_bpermute(addrL, __float_as_int(f.y)));
        float L2 = __int_as_float(__builtin_amdgcn_ds_bpermute(addrL, __float_as_int(f.z)));
        float L3 = __int_as_float(__builtin_amdgcn_ds_bpermute(addrL, __float_as_int(f.w)));
        float R0 = __int_as_float(__builtin_amdgcn_ds_bpermute(addrR, __float_as_int(f.x)));
        float R1 = __int_as_float(__builtin_amdgcn_ds_bpermute(addrR, __float_as_int(f.y)));
        float R2 = __int_as_float(__builtin_amdgcn_ds_bpermute(addrR, __float_as_int(f.z)));
        if (l0)  { L1 = 0.f; L2 = 0.f; L3 = 0.f; }   // cols -3..-1
        if (l63) { R0 = 0.f; R1 = 0.f; R2 = 0.f; }   // cols 256..258

        // win[k] = feat col c0 + k - 4 (k=1..10 used)
        float win[12] = {0.f, L1, L2, L3,
                         f.x, f.y, f.z, f.w,
                         R0, R1, R2, 0.f};
        #pragma unroll
        for (int a = 0; a < 8; ++a) {
            int dh = jj - a;
            if (dh >= 0 && dh <= 6) {
                #pragma unroll
                for (int dw = 0; dw < 7; ++dw) {
                    float wv = wt[dh * 7 + dw];
                    #pragma unroll
                    for (int i = 0; i < 4; ++i)
                        acc[a][i] += win[i + dw + 1] * wv;   // col c0+i+dw-3
                }
            }
        }
    }

    float* obase = out + (size_t)((n * 128 + c) * 256 + H0) * 256 + c0;
    #pragma unroll
    for (int a = 0; a < 8; ++a) {
        fx4 v = {acc[a][0], acc[a][1], acc[a][2], acc[a][3]};
        __builtin_nontemporal_store(v, (fx4*)(obase + (size_t)(a * 256)));
    }
}

extern "C" void kernel_launch(void* const* d_in, const int* in_sizes, int n_in,
                              void* d_out, int out_size, void* d_ws, size_t ws_size,
                              hipStream_t stream) {
    const float* feat = (const float*)d_in[0];
    const float* filt = (const float*)d_in[1];
    float* out = (float*)d_out;
    dim3 grid(2 * 128 * 4);               // 1024 blocks x 8 waves
    dim3 block(512);
    hipLaunchKernelGGL(block_fac_kernel, grid, block, 0, stream, feat, filt, out);
}

// Round 15
// 63.526 us; speedup vs baseline: 1.2694x; 1.2694x over previous
//
#include <hip/hip_runtime.h>
#include <stdint.h>

// Block-factorized depthwise 7x7 conv, per-(n,c,8x8-block) filters.
// feat: [N=2, C=128, H=256, W=256] f32 (NCHW)
// filters_lr: [N, C*49, 32, 32] f32 ; weight[n,hb,wb,c,t] = filt[n, c*49+t, hb, wb]
// out[n,c,h,w] = sum_t feat[n,c,h+dh-3,w+dw-3] * weight[n,h/8,w/8,c,t], t=dh*7+dw
//
// Coalesced-weight test in the known-good codegen vehicle (256-thread blocks,
// launch_bounds(256,1) -- 512-thr r14 spilled 110MB at a 128-VGPR box).
// Block = 4 waves = one hb QUARTET of one (n,c):
//  - weights: per tap the quartet slice [4hb x 32wb] = 512B contiguous; one
//    global_load_lds width-16 covers taps {2i,2i+1} (lane l -> tap 2i+(l>>5),
//    byte off (l&31)*16). 25 instrs/block of 512B DRAM bursts vs r12's
//    128B@4KB scatter (suspected 3.25 TB/s ceiling). Instr 24: lanes 32-63
//    exec-masked off (tap 48 only).
//  - LDS s_w[t][hb_local*32+wb] falls out linearly; reg hoist = b32 at bank
//    wb, lane-pair broadcast, conflict-free.
//  - nt output stores (ext_vector_type; HIP float4 class rejected): keep the
//    64MB write stream from evicting L3-resident inputs.
// Compute per wave byte-identical to r12: 14 clamped float4 row loads,
// bpermute halo, 1568 FMAs, 8 stores.

#define NW 4   // waves per block

typedef const uint32_t __attribute__((address_space(1))) guint;
typedef uint32_t __attribute__((address_space(3))) luint;
typedef float __attribute__((ext_vector_type(4))) fx4;

__global__ __launch_bounds__(256, 1)
void block_fac_kernel(const float* __restrict__ feat,
                      const float* __restrict__ filt,
                      float* __restrict__ out) {
    __shared__ float s_w[49 * 4 * 32];    // [t][hb_local][wb], 25088 B

    const int bid  = blockIdx.x;          // ((n*128)+c)*8 + q
    const int q    = bid & 7;             // hb quartet
    const int c    = (bid >> 3) & 127;
    const int n    = bid >> 10;
    const int wave = threadIdx.x >> 6;    // 0..3 = hb_local
    const int lane = threadIdx.x & 63;

    const int hb = q * 4 + wave;          // this wave's weight block row
    const int H0 = hb * 8;                // first output row
    const int c0 = lane << 2;             // output col base (0..252)
    const int wb = lane >> 1;             // weight block col (0..31)

    const float* fbase  = feat + (size_t)(n * 128 + c) * 65536;
    // quartet base inside tap t: filt[.., t, hb=4q, wb=0] = t*1024 + q*128
    const float* wtbase = filt + (size_t)((n * 128 + c) * 49) * 1024 + q * 128;

    // ---- coalesced weight staging: 25 gld_lds, 2 taps (2x512B bursts) each
    for (int i = wave; i < 25; i += NW) { // wave-uniform trip count
        int t = 2 * i + (lane >> 5);
        if (t < 49) {                     // divergent only on instr 24
            const float* gp = wtbase + (size_t)t * 1024 + ((lane & 31) << 2);
            float* lp = s_w + i * 256;    // uniform dest; HW adds lane*16B
            __builtin_amdgcn_global_load_lds((guint*)gp, (luint*)lp, 16, 0, 0);
        }
    }

    // ---- 14 input rows: own float4, clamped address -> unconditional
    float4 row[14];
    #pragma unroll
    for (int r = 0; r < 14; ++r) {
        int gr  = H0 - 3 + r;
        int grc = gr < 0 ? 0 : (gr > 255 ? 255 : gr);
        row[r] = *(const float4*)(fbase + (size_t)grc * 256 + c0);
    }

    __syncthreads();                      // drains weight-LDS + row loads together

    // ---- weights LDS -> reg: 49 b32, bank = wb, lane-pair broadcast
    const float* ws = s_w + wave * 32 + wb;
    float wt[49];
    #pragma unroll
    for (int t = 0; t < 49; ++t) wt[t] = ws[t * 128];

    const int addrL = ((lane - 1) & 63) << 2;   // bpermute: pull from lane-1
    const int addrR = ((lane + 1) & 63) << 2;   // pull from lane+1
    const bool l0  = (lane == 0);
    const bool l63 = (lane == 63);

    float acc[8][4] = {};

    #pragma unroll
    for (int jj = 0; jj < 14; ++jj) {     // input row H0-3+jj ; out row a uses dh=jj-a
        const int gr = H0 - 3 + jj;       // wave-uniform validity
        float4 f = row[jj];
        if (gr < 0 || gr > 255) f = make_float4(0.f, 0.f, 0.f, 0.f);

        float L1 = __int_as_float(__builtin_amdgcn_ds_bpermute(addrL, __float_as_int(f.y)));
        float L2 = __int_as_float(__builtin_amdgcn_ds_bpermute(addrL, __float_as_int(f.z)));
        float L3 = __int_as_float(__builtin_amdgcn_ds_bpermute(addrL, __float_as_int(f.w)));
        float R0 = __int_as_float(__builtin_amdgcn_ds_bpermute(addrR, __float_as_int(f.x)));
        float R1 = __int_as_float(__builtin_amdgcn_ds_bpermute(addrR, __float_as_int(f.y)));
        float R2 = __int_as_float(__builtin_amdgcn_ds_bpermute(addrR, __float_as_int(f.z)));
        if (l0)  { L1 = 0.f; L2 = 0.f; L3 = 0.f; }   // cols -3..-1
        if (l63) { R0 = 0.f; R1 = 0.f; R2 = 0.f; }   // cols 256..258

        // win[k] = feat col c0 + k - 4 (k=1..10 used)
        float win[12] = {0.f, L1, L2, L3,
                         f.x, f.y, f.z, f.w,
                         R0, R1, R2, 0.f};
        #pragma unroll
        for (int a = 0; a < 8; ++a) {
            int dh = jj - a;
            if (dh >= 0 && dh <= 6) {
                #pragma unroll
                for (int dw = 0; dw < 7; ++dw) {
                    float wv = wt[dh * 7 + dw];
                    #pragma unroll
                    for (int i = 0; i < 4; ++i)
                        acc[a][i] += win[i + dw + 1] * wv;   // col c0+i+dw-3
                }
            }
        }
    }

    float* obase = out + (size_t)((n * 128 + c) * 256 + H0) * 256 + c0;
    #pragma unroll
    for (int a = 0; a < 8; ++a) {
        fx4 v = {acc[a][0], acc[a][1], acc[a][2], acc[a][3]};
        __builtin_nontemporal_store(v, (fx4*)(obase + (size_t)(a * 256)));
    }
}

extern "C" void kernel_launch(void* const* d_in, const int* in_sizes, int n_in,
                              void* d_out, int out_size, void* d_ws, size_t ws_size,
                              hipStream_t stream) {
    const float* feat = (const float*)d_in[0];
    const float* filt = (const float*)d_in[1];
    float* out = (float*)d_out;
    dim3 grid(2 * 128 * 8);               // 2048 blocks x 4 waves
    dim3 block(256);
    hipLaunchKernelGGL(block_fac_kernel, grid, block, 0, stream, feat, filt, out);
}